// Round 3
// baseline (26442.590 us; speedup 1.0000x reference)
//
#include <hip/hip_runtime.h>

typedef unsigned short u16;
typedef unsigned int   u32;

#define NTHREADS 512
#define NBLOCKS  256
#define BB       2
#define STEPS    1024
#define TPTS     1025
#define HDIM     64
#define NZ       16
#define WID      128
#define IND      65
#define HN       1024

__device__ __forceinline__ float bf2f(u16 v) { return __uint_as_float(((u32)v) << 16); }
__device__ __forceinline__ u16 f2bf(float f) {
    u32 u = __float_as_uint(f);
    return (u16)((u + 0x7fffu + ((u >> 16) & 1u)) >> 16);
}
__device__ __forceinline__ float lo16(u32 u) { return __uint_as_float(u << 16); }
__device__ __forceinline__ float hi16(u32 u) { return __uint_as_float(u & 0xffff0000u); }
__device__ __forceinline__ u32 pk(float a, float b) {
    return (u32)f2bf(a) | ((u32)f2bf(b) << 16);
}

// runtime-dtype loads: is32 ? fp32 buffer : bf16 buffer
__device__ __forceinline__ float ldf(const void* p, int i, bool is32) {
    return is32 ? ((const float*)p)[i] : bf2f(((const u16*)p)[i]);
}
__device__ __forceinline__ u16 ldbf(const void* p, int i, bool is32) {
    return is32 ? f2bf(((const float*)p)[i]) : ((const u16*)p)[i];
}

__device__ __forceinline__ float lipswish(float x) {
    return 0.909f * x / (1.0f + __expf(-x));
}
__device__ __forceinline__ float tanh_fast(float x) {
    float e = __expf(2.0f * fabsf(x));   // may be +inf -> t = 1
    float t = 1.0f - 2.0f / (e + 1.0f);
    return copysignf(t, x);
}

struct __align__(16) SMem {
    u32 vW0p[WID][33];    // pairs of bf16 along K (65 -> 33 pairs, last hi=0)
    u32 cW0p[WID][33];
    u32 vW1p[WID][65];    // 64 pairs + 1 pad column
    u32 cW1p[WID][65];
    u32 vW2p[HDIM][65];
    float vb0[WID], vb1[WID], vb2[HDIM], vsc[HDIM];
    float cb0[WID], cb1[WID];
    float cb2[HN];
    float csc[HN];
    float roW[8][HDIM];
    float rob[8];
    float tsb[1028];
    float x[BB][68];      // [t, y(64), 0pad]; stride 68 keeps rows 16B-aligned
    float h1[2][BB][WID];
    float h2[2][BB][WID];
    float yb[BB][HDIM];
    float fdt[BB][HDIM];
    float g0b[BB][HDIM];
    float gs[BB][HDIM];
    float dwb[BB][NZ];
};

__device__ __forceinline__ float dot64p(const u32* __restrict__ Wp, const float2* __restrict__ xp) {
    float a0 = 0.f, a1 = 0.f, a2 = 0.f, a3 = 0.f;
    #pragma unroll
    for (int kk = 0; kk < 64; kk += 4) {
        u32 w0 = Wp[kk], w1 = Wp[kk+1], w2 = Wp[kk+2], w3 = Wp[kk+3];
        float2 x0 = xp[kk], x1 = xp[kk+1], x2 = xp[kk+2], x3 = xp[kk+3];
        a0 = fmaf(lo16(w0), x0.x, fmaf(hi16(w0), x0.y, a0));
        a1 = fmaf(lo16(w1), x1.x, fmaf(hi16(w1), x1.y, a1));
        a2 = fmaf(lo16(w2), x2.x, fmaf(hi16(w2), x2.y, a2));
        a3 = fmaf(lo16(w3), x3.x, fmaf(hi16(w3), x3.y, a3));
    }
    return (a0 + a1) + (a2 + a3);
}

__device__ __forceinline__ float dot33p(const u32* __restrict__ Wp, const float2* __restrict__ xp) {
    float a0 = 0.f, a1 = 0.f, a2 = 0.f, a3 = 0.f;
    #pragma unroll
    for (int kk = 0; kk < 32; kk += 4) {
        u32 w0 = Wp[kk], w1 = Wp[kk+1], w2 = Wp[kk+2], w3 = Wp[kk+3];
        float2 x0 = xp[kk], x1 = xp[kk+1], x2 = xp[kk+2], x3 = xp[kk+3];
        a0 = fmaf(lo16(w0), x0.x, fmaf(hi16(w0), x0.y, a0));
        a1 = fmaf(lo16(w1), x1.x, fmaf(hi16(w1), x1.y, a1));
        a2 = fmaf(lo16(w2), x2.x, fmaf(hi16(w2), x2.y, a2));
        a3 = fmaf(lo16(w3), x3.x, fmaf(hi16(w3), x3.y, a3));
    }
    u32 wl = Wp[32]; float2 xv = xp[32];
    a0 = fmaf(lo16(wl), xv.x, fmaf(hi16(wl), xv.y, a0));
    return (a0 + a1) + (a2 + a3);
}

// function, not macro (Round 1: macro param 'w' collided with member '.w')
__device__ __forceinline__ void bigrow(float& acc, const uint4& wv, const float4& pv, const float4& qv) {
    acc = fmaf(lo16(wv.x), pv.x, acc);
    acc = fmaf(hi16(wv.x), pv.y, acc);
    acc = fmaf(lo16(wv.y), pv.z, acc);
    acc = fmaf(hi16(wv.y), pv.w, acc);
    acc = fmaf(lo16(wv.z), qv.x, acc);
    acc = fmaf(hi16(wv.z), qv.y, acc);
    acc = fmaf(lo16(wv.w), qv.z, acc);
    acc = fmaf(hi16(wv.w), qv.w, acc);
}

__device__ __forceinline__ void big_layer(SMem& sm, const uint4 (&wr)[32], int tid) {
    const int r0 = 2 * tid;
    float a00 = sm.cb2[r0], a01 = sm.cb2[r0 + 1];
    float a10 = a00, a11 = a01;
    const float4* hA = (const float4*)sm.h2[1][0];
    const float4* hB = (const float4*)sm.h2[1][1];
    #pragma unroll
    for (int i = 0; i < 16; ++i) {
        uint4 wa = wr[i];
        uint4 wb = wr[16 + i];
        float4 p0 = hA[2*i], q0 = hA[2*i + 1];
        float4 p1 = hB[2*i], q1 = hB[2*i + 1];
        bigrow(a00, wa, p0, q0);
        bigrow(a01, wb, p0, q0);
        bigrow(a10, wa, p1, q1);
        bigrow(a11, wb, p1, q1);
    }
    const float c0 = sm.csc[r0], c1 = sm.csc[r0 + 1];
    const int n0 = r0 & 15;
    float v0 = c0 * tanh_fast(a00) * sm.dwb[0][n0] + c1 * tanh_fast(a01) * sm.dwb[0][n0 + 1];
    float v1 = c0 * tanh_fast(a10) * sm.dwb[1][n0] + c1 * tanh_fast(a11) * sm.dwb[1][n0 + 1];
    #pragma unroll
    for (int m = 1; m < 8; m <<= 1) {
        v0 += __shfl_xor(v0, m);
        v1 += __shfl_xor(v1, m);
    }
    if ((tid & 7) == 0) {
        sm.gs[0][tid >> 3] = v0;
        sm.gs[1][tid >> 3] = v1;
    }
}

__device__ __forceinline__ void stage_dw(SMem& sm, const uint4& d, int q, bool is32, float sdt) {
    if (is32) {
        // q in [0,8): 4 fp32 values, flat f = q*4 over [sample(2)][noise(16)]
        const float* pf = (const float*)&d;
        int f = q * 4;
        #pragma unroll
        for (int k = 0; k < 4; ++k)
            sm.dwb[(f + k) >> 4][(f + k) & 15] = pf[k] * sdt;
    } else {
        // q in [0,4): 8 bf16 values, flat f = q*8
        int f = q * 8;
        u32 u0 = d.x, u1 = d.y, u2 = d.z, u3 = d.w;
        sm.dwb[(f    ) >> 4][(f    ) & 15] = lo16(u0) * sdt;
        sm.dwb[(f + 1) >> 4][(f + 1) & 15] = hi16(u0) * sdt;
        sm.dwb[(f + 2) >> 4][(f + 2) & 15] = lo16(u1) * sdt;
        sm.dwb[(f + 3) >> 4][(f + 3) & 15] = hi16(u1) * sdt;
        sm.dwb[(f + 4) >> 4][(f + 4) & 15] = lo16(u2) * sdt;
        sm.dwb[(f + 5) >> 4][(f + 5) & 15] = hi16(u2) * sdt;
        sm.dwb[(f + 6) >> 4][(f + 6) & 15] = lo16(u3) * sdt;
        sm.dwb[(f + 7) >> 4][(f + 7) & 15] = hi16(u3) * sdt;
    }
}

__device__ __forceinline__ void write_out(void* out, bool is32, size_t idx, const float* v8) {
    if (is32) {
        float4 o0, o1;
        o0.x = v8[0]; o0.y = v8[1]; o0.z = v8[2]; o0.w = v8[3];
        o1.x = v8[4]; o1.y = v8[5]; o1.z = v8[6]; o1.w = v8[7];
        ((float4*)out)[idx * 2]     = o0;
        ((float4*)out)[idx * 2 + 1] = o1;
    } else {
        uint4 o;
        o.x = pk(v8[0], v8[1]);
        o.y = pk(v8[2], v8[3]);
        o.z = pk(v8[4], v8[5]);
        o.w = pk(v8[6], v8[7]);
        ((uint4*)out)[idx] = o;
    }
}

__global__ void __launch_bounds__(NTHREADS, 2)
sde_kernel(const void* __restrict__ ts,  const void* __restrict__ z0,  const void* __restrict__ dW,
           const void* __restrict__ iW0, const void* __restrict__ ib0, const void* __restrict__ iW1,
           const void* __restrict__ ib1, const void* __restrict__ iW2, const void* __restrict__ ib2,
           const void* __restrict__ vW0, const void* __restrict__ vb0, const void* __restrict__ vW1,
           const void* __restrict__ vb1, const void* __restrict__ vW2, const void* __restrict__ vb2,
           const void* __restrict__ vsc, const void* __restrict__ cW0, const void* __restrict__ cb0,
           const void* __restrict__ cW1, const void* __restrict__ cb1, const void* __restrict__ cW2,
           const void* __restrict__ cb2, const void* __restrict__ csc, const void* __restrict__ roW,
           const void* __restrict__ rob, void* __restrict__ out)
{
    __shared__ SMem sm;
    const int tid  = threadIdx.x;
    const int bid  = blockIdx.x;

    // dtype detection: u16 word #1 of ts. bf16: bf16(1/1024)=0x3A80 != 0.
    // fp32: high half of 0.0f == 0.
    const bool is32 = (((const u16*)ts)[1] == 0);

    // ---- cW2 rows 2*tid, 2*tid+1 -> registers (bf16-packed either way) ----
    uint4 wr[32];
    if (!is32) {
        const uint4* p0 = (const uint4*)((const u16*)cW2 + (size_t)(2 * tid)     * WID);
        const uint4* p1 = (const uint4*)((const u16*)cW2 + (size_t)(2 * tid + 1) * WID);
        #pragma unroll
        for (int i = 0; i < 16; ++i) wr[i] = p0[i];
        #pragma unroll
        for (int i = 0; i < 16; ++i) wr[16 + i] = p1[i];
    } else {
        const float4* f0 = (const float4*)((const float*)cW2 + (size_t)(2 * tid)     * WID);
        const float4* f1 = (const float4*)((const float*)cW2 + (size_t)(2 * tid + 1) * WID);
        #pragma unroll
        for (int i = 0; i < 16; ++i) {
            float4 a = f0[2*i], b = f0[2*i+1];
            uint4 w; w.x = pk(a.x, a.y); w.y = pk(a.z, a.w); w.z = pk(b.x, b.y); w.w = pk(b.z, b.w);
            wr[i] = w;
        }
        #pragma unroll
        for (int i = 0; i < 16; ++i) {
            float4 a = f1[2*i], b = f1[2*i+1];
            uint4 w; w.x = pk(a.x, a.y); w.y = pk(a.z, a.w); w.z = pk(b.x, b.y); w.w = pk(b.z, b.w);
            wr[16 + i] = w;
        }
    }

    // ---- stage weights into LDS as packed bf16 pairs ----
    for (int idx = tid; idx < WID * 33; idx += NTHREADS) {
        int j = idx / 33, kk = idx - j * 33;
        int k0 = 2 * kk;
        u32 lo, hi;
        lo = ldbf(vW0, j * IND + k0, is32);
        hi = (k0 + 1 < IND) ? (u32)ldbf(vW0, j * IND + k0 + 1, is32) : 0u;
        sm.vW0p[j][kk] = lo | (hi << 16);
        lo = ldbf(cW0, j * IND + k0, is32);
        hi = (k0 + 1 < IND) ? (u32)ldbf(cW0, j * IND + k0 + 1, is32) : 0u;
        sm.cW0p[j][kk] = lo | (hi << 16);
    }
    for (int idx = tid; idx < WID * 65; idx += NTHREADS) {
        int j = idx / 65, kk = idx - j * 65;
        u32 v = 0, c = 0;
        if (kk < 64) {
            int k0 = 2 * kk;
            v = (u32)ldbf(vW1, j * WID + k0, is32) | ((u32)ldbf(vW1, j * WID + k0 + 1, is32) << 16);
            c = (u32)ldbf(cW1, j * WID + k0, is32) | ((u32)ldbf(cW1, j * WID + k0 + 1, is32) << 16);
        }
        sm.vW1p[j][kk] = v;
        sm.cW1p[j][kk] = c;
    }
    for (int idx = tid; idx < HDIM * 65; idx += NTHREADS) {
        int j = idx / 65, kk = idx - j * 65;
        u32 v = 0;
        if (kk < 64) {
            int k0 = 2 * kk;
            v = (u32)ldbf(vW2, j * WID + k0, is32) | ((u32)ldbf(vW2, j * WID + k0 + 1, is32) << 16);
        }
        sm.vW2p[j][kk] = v;
    }
    if (tid < WID) {
        sm.vb0[tid] = ldf(vb0, tid, is32); sm.vb1[tid] = ldf(vb1, tid, is32);
        sm.cb0[tid] = ldf(cb0, tid, is32); sm.cb1[tid] = ldf(cb1, tid, is32);
        if (tid < HDIM) { sm.vb2[tid] = ldf(vb2, tid, is32); sm.vsc[tid] = ldf(vsc, tid, is32); }
        if (tid < 8) sm.rob[tid] = ldf(rob, tid, is32);
    }
    for (int i = tid; i < HN; i += NTHREADS) {
        sm.cb2[i] = ldf(cb2, i, is32);
        sm.csc[i] = ldf(csc, i, is32);
    }
    { int d = tid >> 6, i2 = tid & 63; sm.roW[d][i2] = ldf(roW, tid, is32); }
    for (int i = tid; i < TPTS; i += NTHREADS) sm.tsb[i] = ldf(ts, i, is32);

    // prefetch dW for step 0
    uint4 dwpref;
    if (tid >= 128 && tid < 136) {
        int q = tid - 128;
        if (is32)       dwpref = ((const uint4*)dW)[(size_t)bid * 8 + q];       // 8 x float4
        else if (q < 4) dwpref = ((const uint4*)dW)[(size_t)bid * 4 + q];       // 4 x bf16x8
    }

    __syncthreads();

    const float dt  = sm.tsb[1] - sm.tsb[0];
    const float sdt = sqrtf(dt);

    if (tid >= 128 && tid < 136) {
        int q = tid - 128;
        if (is32 || q < 4) stage_dw(sm, dwpref, q, is32, sdt);
    }

    // ---- initial MLP (relu, relu, identity): z0(8) -> 128 -> 128 -> y0(64) ----
    if (tid < 256) {   // I1
        int b = tid >> 7, j = tid & 127;
        float acc = ldf(ib0, j, is32);
        #pragma unroll
        for (int k = 0; k < 8; ++k)
            acc = fmaf(ldf(iW0, j * 8 + k, is32), ldf(z0, (bid * BB + b) * 8 + k, is32), acc);
        sm.h1[0][b][j] = fmaxf(acc, 0.0f);
    }
    __syncthreads();
    if (tid < 256) {   // I2
        int b = tid >> 7, j = tid & 127;
        float acc = ldf(ib1, j, is32);
        for (int k = 0; k < WID; ++k)
            acc = fmaf(ldf(iW1, j * WID + k, is32), sm.h1[0][b][k], acc);
        sm.h2[0][b][j] = fmaxf(acc, 0.0f);
    }
    __syncthreads();
    if (tid < 128) {   // I3: y0, x init, t=0 readout
        int b = tid >> 6, i = tid & 63;
        float y0 = ldf(ib2, i, is32);
        for (int k = 0; k < WID; ++k)
            y0 = fmaf(ldf(iW2, i * WID + k, is32), sm.h2[0][b][k], y0);
        sm.yb[b][i] = y0;
        sm.x[b][1 + i] = y0;
        if (i == 0) {
            sm.x[b][0] = sm.tsb[0];
            sm.x[b][65] = 0.0f; sm.x[b][66] = 0.0f; sm.x[b][67] = 0.0f;
        }
        float acc[8];
        #pragma unroll
        for (int d = 0; d < 8; ++d) acc[d] = sm.roW[d][i] * y0;
        #pragma unroll
        for (int m = 1; m < 64; m <<= 1) {
            #pragma unroll
            for (int d = 0; d < 8; ++d) acc[d] += __shfl_xor(acc[d], m);
        }
        if (i == 0) {
            float v8[8];
            #pragma unroll
            for (int d = 0; d < 8; ++d) v8[d] = acc[d] + sm.rob[d];
            write_out(out, is32, (size_t)(bid * BB + b) * TPTS, v8);
        }
    }
    __syncthreads();

    // ---- main scan: 1024 Euler-Heun steps ----
    for (int s = 0; s < STEPS; ++s) {
        if (s + 1 < STEPS && tid >= 128 && tid < 136) {
            int q = tid - 128;
            if (is32)       dwpref = ((const uint4*)dW)[(size_t)(s + 1) * 2048 + bid * 8 + q];
            else if (q < 4) dwpref = ((const uint4*)dW)[(size_t)(s + 1) * 1024 + bid * 4 + q];
        }
        // P2: fused L0 for drift(v=0) and diffusion(c=1), input x=[t,y]
        {
            const int mlp = tid >> 8, b = (tid >> 7) & 1, j = tid & 127;
            const u32* Wp = mlp ? sm.cW0p[j] : sm.vW0p[j];
            const float bias = mlp ? sm.cb0[j] : sm.vb0[j];
            float acc = bias + dot33p(Wp, (const float2*)sm.x[b]);
            sm.h1[mlp][b][j] = lipswish(acc);
        }
        __syncthreads();
        // P3: fused L1
        {
            const int mlp = tid >> 8, b = (tid >> 7) & 1, j = tid & 127;
            const u32* Wp = mlp ? sm.cW1p[j] : sm.vW1p[j];
            const float bias = mlp ? sm.cb1[j] : sm.vb1[j];
            float acc = bias + dot64p(Wp, (const float2*)sm.h1[mlp][b]);
            sm.h2[mlp][b][j] = lipswish(acc);
        }
        __syncthreads();
        // P4: diffusion big layer eval 1 -> gs = g0
        big_layer(sm, wr, tid);
        __syncthreads();
        // P5: x' = y + g0 (waves 0-1) | drift L2 -> fdt (waves 2-3)
        if (tid < 128) {
            int b = tid >> 6, i = tid & 63;
            float g0 = sm.gs[b][i];
            sm.g0b[b][i] = g0;
            sm.x[b][1 + i] = sm.yb[b][i] + g0;
        } else if (tid < 256) {
            int q = tid - 128, b = q >> 6, j = q & 63;
            float acc = sm.vb2[j] + dot64p(sm.vW2p[j], (const float2*)sm.h2[0][b]);
            sm.fdt[b][j] = sm.vsc[j] * tanh_fast(acc) * dt;
        }
        __syncthreads();
        // P6: diffusion L0 on x'
        if (tid < 256) {
            int b = tid >> 7, j = tid & 127;
            float acc = sm.cb0[j] + dot33p(sm.cW0p[j], (const float2*)sm.x[b]);
            sm.h1[1][b][j] = lipswish(acc);
        }
        __syncthreads();
        // P7: diffusion L1
        if (tid < 256) {
            int b = tid >> 7, j = tid & 127;
            float acc = sm.cb1[j] + dot64p(sm.cW1p[j], (const float2*)sm.h1[1][b]);
            sm.h2[1][b][j] = lipswish(acc);
        }
        __syncthreads();
        // P8: diffusion big layer eval 2 -> gs = g1
        big_layer(sm, wr, tid);
        __syncthreads();
        // P9: y1 = y + f0*dt + 0.5*(g0+g1); readout; stage next x and dw
        if (tid < 128) {
            int b = tid >> 6, i = tid & 63;
            float y1 = sm.yb[b][i] + sm.fdt[b][i] + 0.5f * (sm.g0b[b][i] + sm.gs[b][i]);
            sm.yb[b][i] = y1;
            sm.x[b][1 + i] = y1;
            if (i == 0) sm.x[b][0] = sm.tsb[s + 1];
            float acc[8];
            #pragma unroll
            for (int d = 0; d < 8; ++d) acc[d] = sm.roW[d][i] * y1;
            #pragma unroll
            for (int m = 1; m < 64; m <<= 1) {
                #pragma unroll
                for (int d = 0; d < 8; ++d) acc[d] += __shfl_xor(acc[d], m);
            }
            if (i == 0) {
                float v8[8];
                #pragma unroll
                for (int d = 0; d < 8; ++d) v8[d] = acc[d] + sm.rob[d];
                write_out(out, is32, (size_t)(bid * BB + b) * TPTS + (s + 1), v8);
            }
        } else if (tid >= 128 && tid < 136 && s + 1 < STEPS) {
            int q = tid - 128;
            if (is32 || q < 4) stage_dw(sm, dwpref, q, is32, sdt);
        }
        __syncthreads();
    }
}

extern "C" void kernel_launch(void* const* d_in, const int* in_sizes, int n_in,
                              void* d_out, int out_size, void* d_ws, size_t ws_size,
                              hipStream_t stream) {
    (void)in_sizes; (void)n_in; (void)d_ws; (void)ws_size; (void)out_size;
    hipLaunchKernelGGL(sde_kernel, dim3(NBLOCKS), dim3(NTHREADS), 0, stream,
                       d_in[0], d_in[1], d_in[2], d_in[3], d_in[4], d_in[5], d_in[6],
                       d_in[7], d_in[8], d_in[9], d_in[10], d_in[11], d_in[12], d_in[13],
                       d_in[14], d_in[15], d_in[16], d_in[17], d_in[18], d_in[19], d_in[20],
                       d_in[21], d_in[22], d_in[23], d_in[24], d_out);
}